// Round 8
// baseline (97.866 us; speedup 1.0000x reference)
//
#include <hip/hip_runtime.h>
#include <math.h>

// ---------------------------------------------------------------------------
// FullGaussianProjector: B=1, N=512, 3 views, 224x224 out, half-res 112x112.
// R13: ONE fused kernel (normal launch, graph-capturable) + tiny memset.
//   Rationale (R12 post-mortem): 3 short dispatches pay ~25us of pipeline
//   latency; R2 proved 1-dispatch works but lost 30us to single-counter
//   barriers + 15us to KSPLIT=1 imbalance. This kernel combines every
//   proven fix in one launch:
//   - grid (14,14,6), 256 thr: z = v*2+kk, KSPLIT=2 splat split.
//     All 1176 blocks co-resident (LDS 21.7KB -> 7 blocks/CU).
//   - setup recomputed per block (deterministic across blocks; ~0.25us,
//     TLP-hidden; 1176 not 2352 blocks, unlike R10's regression).
//   - cheap barrier A (R9-proven): spread arrival over 32 cachelines,
//     single poller (block 0), read-only release spin. No cache flush;
//     all cross-block data via relaxed agent-scope atomics.
//   - kk=1 blocks EXIT after arrival A -> frees CUs for blur phase.
//   - blur phase (588 kk=0 blocks): quad-grain merge of 2 partial planes,
//     closed-form dmv, blur2 in LDS, d2 stays in registers.
//   - barrier B + poller-only stats (R12-proven): block 0 reduces 588
//     partials in double, publishes (mean, inv); others read 2 floats.
//   - out written exactly once, from registers.
// Closed forms:
//   dmv = 0.5*(S - 512*mn)/(mx - mn + eps) + S/(S + eps)
//   bilinear(quadratic) = quad(Ex,Ey) - (a*Vx + c*Vy)
// NOTE (R5 lesson): a,2b,c,op must stay f32 — bf16 on the exponent path
// fails absmax through the (wmax-wmin) normalization.
// ---------------------------------------------------------------------------

#define NB_ALL 1176u           // barrier A population (splat sub-blocks)
#define NB_BLUR 588u           // barrier B population (kk==0 blocks)
#define NARR 32
// cnts layout (u32 indices; each counter/flag on its own 128B line):
#define CNTA_BASE 0            // 32 lines: i*32
#define FLAGA_IDX 1024
#define CNTB_BASE 1056         // 32 lines: 1056 + i*32
#define FLAGB_IDX 2080
#define STAT_IDX  2112         // (mean, inv) floats
#define CNTS_U32  2144
// part[] SoA planes (KSPLIT=2): plane (kk*3+v), float4 per half-res quad
#define QOFF 12544             // 112*112 quads
#define MNOFF 301056           // 6*QOFF*4 floats of S planes
#define MXOFF 602112

__device__ __forceinline__ float g_ld(const float* p) {
    return __hip_atomic_load(p, __ATOMIC_RELAXED, __HIP_MEMORY_SCOPE_AGENT);
}
__device__ __forceinline__ void g_st(float* p, float v) {
    __hip_atomic_store(p, v, __ATOMIC_RELAXED, __HIP_MEMORY_SCOPE_AGENT);
}

__device__ __forceinline__ float wave_min(float v) {
    #pragma unroll
    for (int o = 32; o >= 1; o >>= 1) v = fminf(v, __shfl_xor(v, o));
    return v;
}

struct SpS {  // splat phase
    float4 lsA[512];                 // a, 2b, c, op
    float2 lsB[512];                 // gx, gy
    float4 pS[3][64], pMn[3][64], pMx[3][64];  // waves 1..3 merge
    float red[4 * 6];
    int gcnt[8];                     // per (g,wave) cull counts, det. scan
};
struct BlS {  // blur phase
    float A[28 * 29];
    float T[28 * 29];
    float r1[4], r2[4];
};
struct NmS {  // stats phase
    double s1[256], s2[256];
    float statLds[2];
};
union SmU { SpS sp; BlS bl; NmS nm; };  // ~21.7 KB

__global__ __launch_bounds__(256, 5) void fused_kernel(
    const float* __restrict__ position, const float* __restrict__ cov3d,
    const float* __restrict__ opacity, const float* __restrict__ importance,
    float* __restrict__ part, float2* __restrict__ partials,
    float* __restrict__ out, unsigned* __restrict__ cnts) {
    __shared__ SmU sm;
    const int v  = blockIdx.z >> 1;
    const int kk = blockIdx.z & 1;
    // hot-tile spreading permutation (gcd(5,14)=1), proven R7/R2
    const int pbx = (5 * blockIdx.x) % 14;
    const int pby = (5 * blockIdx.y) % 14;
    const int tx0 = pbx * 16, ty0 = pby * 16;
    const int tid = threadIdx.x;
    const int lane = tid & 63, wave = tid >> 6;          // 4 waves
    const int bid6 = (int)(blockIdx.z * 196 + blockIdx.y * 14 + blockIdx.x);

    // ============ phase 0: setup (2 gaussians/thread, deterministic) ============
    float P0[3], P1[3], OP0, OP1;
    {
        const int n0 = tid, n1 = tid + 256;
        P0[0] = position[n0 * 3 + 0]; P0[1] = position[n0 * 3 + 1]; P0[2] = position[n0 * 3 + 2];
        P1[0] = position[n1 * 3 + 0]; P1[1] = position[n1 * 3 + 1]; P1[2] = position[n1 * 3 + 2];
        OP0 = opacity[n0] * fminf(fmaxf(importance[n0], 0.5f), 2.0f);
        OP1 = opacity[n1] * fminf(fmaxf(importance[n1], 0.5f), 2.0f);
    }
    {
        float vals[6] = { fminf(P0[0], P1[0]), fminf(-P0[0], -P1[0]),
                          fminf(P0[1], P1[1]), fminf(-P0[1], -P1[1]),
                          fminf(P0[2], P1[2]), fminf(-P0[2], -P1[2]) };
        #pragma unroll
        for (int k = 0; k < 6; ++k) {
            float r = wave_min(vals[k]);
            if (lane == 0) sm.sp.red[wave * 6 + k] = r;
        }
    }
    __syncthreads();
    float mn6[6];
    #pragma unroll
    for (int k = 0; k < 6; ++k) {
        float r = sm.sp.red[k];
        #pragma unroll
        for (int w = 1; w < 4; ++w) r = fminf(r, sm.sp.red[w * 6 + k]);
        mn6[k] = r;
    }
    const float pmn[3] = {mn6[0], mn6[2], mn6[4]};
    const float pmx[3] = {-mn6[1], -mn6[3], -mn6[5]};
    int ix, iy;
    if (v == 0)      { ix = 0; iy = 1; }
    else if (v == 1) { ix = 0; iy = 2; }
    else             { ix = 2; iy = 1; }
    float mnx = pmn[ix], mxx = pmx[ix], mny = pmn[iy], mxy = pmx[iy];
    float rngx = mxx - mnx + 1e-6f;
    float mnx2 = mnx - 0.5f * rngx;
    float mxx2 = mxx + 0.5f * rngx;
    rngx = mxx2 - mnx2 + 1e-6f;
    float rngy = mxy - mny + 1e-6f;
    float mny2 = mny - 0.5f * rngy;
    float mxy2 = mxy + 0.5f * rngy;
    rngy = mxy2 - mny2 + 1e-6f;
    const float bx0f = (float)(tx0 >> 1), bx1f = (float)((tx0 + 15) >> 1);
    const float by0f = (float)(ty0 >> 1), by1f = (float)((ty0 + 15) >> 1);

    // cull + DETERMINISTIC compact (group order (g<<2)|wave; both kk blocks
    // of a tile build the identical list; chunks partition it exactly)
    float gAa[2], gAb2[2], gAc[2], gOp[2], gGx[2], gGy[2];
    bool gPass[2];
    unsigned long long gM[2];
    #pragma unroll
    for (int g = 0; g < 2; ++g) {
        const int n = tid + (g << 8);
        const float p0 = g ? P1[0] : P0[0];
        const float p1 = g ? P1[1] : P0[1];
        const float p2 = g ? P1[2] : P0[2];
        float c00 = cov3d[n * 9 + 0], c01 = cov3d[n * 9 + 1], c02 = cov3d[n * 9 + 2];
        float c10 = cov3d[n * 9 + 3], c11 = cov3d[n * 9 + 4], c12 = cov3d[n * 9 + 5];
        float c20 = cov3d[n * 9 + 6], c21 = cov3d[n * 9 + 7], c22 = cov3d[n * 9 + 8];
        for (int vv = 0; vv <= v; ++vv) {
            float s01 = 0.5f * (c01 + c10);
            float s02 = 0.5f * (c02 + c20);
            float s12 = 0.5f * (c12 + c21);
            float s00 = c00 + 1e-6f;
            float s11 = c11 + 1e-6f;
            float s22 = c22 + 1e-6f;
            float nrm = sqrtf(s00 * s00 + s11 * s11 + s22 * s22 +
                              2.0f * (s01 * s01 + s02 * s02 + s12 * s12));
            float inv = 1.0f / (nrm + 1e-6f);
            c00 = s00 * inv; c11 = s11 * inv; c22 = s22 * inv;
            c01 = s01 * inv; c10 = c01; c02 = s02 * inv; c20 = c02;
            c12 = s12 * inv; c21 = c12;
        }
        float cof00 = c11 * c22 - c12 * c12;
        float cof01 = c02 * c12 - c01 * c22;
        float cof02 = c01 * c12 - c02 * c11;
        float det = c00 * cof00 + c01 * cof01 + c02 * cof02;
        float idet = 1.0f / det;
        float i00 = cof00 * idet;
        float i01 = cof01 * idet;
        float i02 = cof02 * idet;
        float i11 = (c00 * c22 - c02 * c02) * idet;
        float i12 = (c02 * c01 - c00 * c12) * idet;
        float i22 = (c00 * c11 - c01 * c01) * idet;
        float Aa, Ab, Ac, prx, pry;
        if (v == 0)      { Aa = i00; Ab = i01; Ac = i11; prx = p0; pry = p1; }
        else if (v == 1) { Aa = i00; Ab = i02; Ac = i22; prx = p0; pry = p2; }
        else             { Aa = i22; Ab = i12; Ac = i11; prx = p2; pry = p1; }
        Aa += 1e-10f;
        Ac += 1e-10f;
        float gx = fminf(fmaxf((prx - mnx2) / rngx * 111.0f, 0.0f), 111.0f);
        float gy = fminf(fmaxf((pry - mny2) / rngy * 111.0f, 0.0f), 111.0f);
        gAa[g] = Aa; gAb2[g] = 2.0f * Ab; gAc[g] = Ac;
        gOp[g] = g ? OP1 : OP0; gGx[g] = gx; gGy[g] = gy;
        float dx = fmaxf(fmaxf(bx0f - gx, gx - bx1f), 0.0f);
        float dy = fmaxf(fmaxf(by0f - gy, gy - by1f), 0.0f);
        gPass[g] = (dx * dx + dy * dy) < 400.01f;   // conservative superset
        gM[g] = __ballot(gPass[g]);
        if (lane == 0) sm.sp.gcnt[(g << 2) | wave] = __popcll(gM[g]);
    }
    __syncthreads();
    int len = 0;
    {
        int pre[2] = {0, 0};
        #pragma unroll
        for (int q = 0; q < 8; ++q) {
            int c = sm.sp.gcnt[q];
            #pragma unroll
            for (int g = 0; g < 2; ++g)
                if (q < ((g << 2) | wave)) pre[g] += c;
            len += c;
        }
        #pragma unroll
        for (int g = 0; g < 2; ++g) {
            if (gPass[g]) {
                int slot = pre[g] + __popcll(gM[g] & ((1ull << lane) - 1ull));
                sm.sp.lsA[slot] = make_float4(gAa[g], gAb2[g], gAc[g], gOp[g]);
                sm.sp.lsB[slot] = make_float2(gGx[g], gGy[g]);
            }
        }
    }
    __syncthreads();

    // quad owned by this lane (wave0 writes): half-res pixel (xh, yh)
    const int qx = lane & 7, qy = lane >> 3;
    const int xh = (tx0 >> 1) + qx;
    const int yh = (ty0 >> 1) + qy;

    const int npad = (len + 15) & ~15;
    if (tid < npad - len) {  // no-op pad gaussians (mask always fails -> w=0)
        sm.sp.lsA[len + tid] = make_float4(1.0f, 0.0f, 1.0f, 0.0f);
        sm.sp.lsB[len + tid] = make_float2(1e9f, 1e9f);
    }
    __syncthreads();

    // per-parity constants (generic formula, preserves edge clamping exactly)
    float exA[2], eyA[2], VxA[2], VyA[2];
    #pragma unroll
    for (int p = 0; p < 2; ++p) {
        int xlo = xh - 1 + p; int xhi = min(xlo + 1, 111); xlo = max(xlo, 0);
        float wlo = p ? 0.75f : 0.25f, whi = 1.0f - wlo;
        exA[p] = wlo * (float)xlo + whi * (float)xhi;
        VxA[p] = wlo * whi * (float)(xhi - xlo) * (float)(xhi - xlo);
        int ylo = yh - 1 + p; int yhi2 = min(ylo + 1, 111); ylo = max(ylo, 0);
        eyA[p] = wlo * (float)ylo + whi * (float)yhi2;
        VyA[p] = wlo * whi * (float)(yhi2 - ylo) * (float)(yhi2 - ylo);
    }
    const float fxh = (float)xh, fyh = (float)yh;

    // ------- chunk for (kk, wave): 1/8 of list; npad mult 16 -> chunk even -------
    const int chunk = npad >> 3;
    const int cbeg = ((kk << 2) + wave) * chunk, cend = cbeg + chunk;

    float S00 = 0.f, S01 = 0.f, S10 = 0.f, S11 = 0.f;
    float mn00 = INFINITY, mn01 = INFINITY, mn10 = INFINITY, mn11 = INFINITY;
    float mx00 = -INFINITY, mx01 = -INFINITY, mx10 = -INFINITY, mx11 = -INFINITY;

    for (int i = cbeg; i < cend; i += 2) {
        float4 gA0 = sm.sp.lsA[i], gA1 = sm.sp.lsA[i + 1];
        float2 gB0 = sm.sp.lsB[i], gB1 = sm.sp.lsB[i + 1];
        #pragma unroll
        for (int u = 0; u < 2; ++u) {
            const float4 gA = u ? gA1 : gA0;
            const float2 gB = u ? gB1 : gB0;
            const float a = gA.x, b2 = gA.y, c = gA.z, op = gA.w;
            const float xx = gB.x, yy = gB.y;
            const float dxh = fxh - xx, dyh = fyh - yy;
            const bool inside = dxh * dxh + dyh * dyh < 400.0f;
            const float dx0 = exA[0] - xx, dx1 = exA[1] - xx;
            const float dy0 = eyA[0] - yy, dy1 = eyA[1] - yy;
            const float adx0 = a * dx0, adx1 = a * dx1;
            const float bdy0 = b2 * dy0, bdy1 = b2 * dy1;
            const float cdy0 = c * dy0 * dy0, cdy1 = c * dy1 * dy1;
            const float ax0 = a * VxA[0], ax1 = a * VxA[1];
            const float cy0 = c * VyA[0], cy1 = c * VyA[1];
            #pragma unroll
            for (int py = 0; py < 2; ++py) {
                const float bdyp = py ? bdy1 : bdy0;
                const float cdyp = py ? cdy1 : cdy0;
                const float cyp  = py ? cy1 : cy0;
                #pragma unroll
                for (int px = 0; px < 2; ++px) {
                    const float dxp  = px ? dx1 : dx0;
                    const float adxp = px ? adx1 : adx0;
                    const float axp  = px ? ax1 : ax0;
                    float q = dxp * (adxp + bdyp) + cdyp;
                    float bil = -((q + axp) + cyp);
                    bil = fminf(fmaxf(bil, -20.0f), 0.0f);
                    bil = inside ? bil : -1e9f;   // exp flushes to +0
                    float w = op * __expf(bil);
                    if (py == 0 && px == 0) { S00 += w; mn00 = fminf(mn00, w); mx00 = fmaxf(mx00, w); }
                    if (py == 0 && px == 1) { S01 += w; mn01 = fminf(mn01, w); mx01 = fmaxf(mx01, w); }
                    if (py == 1 && px == 0) { S10 += w; mn10 = fminf(mn10, w); mx10 = fmaxf(mx10, w); }
                    if (py == 1 && px == 1) { S11 += w; mn11 = fminf(mn11, w); mx11 = fmaxf(mx11, w); }
                }
            }
        }
    }
    if (wave > 0) {
        sm.sp.pS[wave - 1][lane]  = make_float4(S00, S01, S10, S11);
        sm.sp.pMn[wave - 1][lane] = make_float4(mn00, mn01, mn10, mn11);
        sm.sp.pMx[wave - 1][lane] = make_float4(mx00, mx01, mx10, mx11);
    }
    __syncthreads();
    if (wave == 0) {
        #pragma unroll
        for (int w = 0; w < 3; ++w) {
            float4 s = sm.sp.pS[w][lane], mnw = sm.sp.pMn[w][lane], mxw = sm.sp.pMx[w][lane];
            S00 += s.x; S01 += s.y; S10 += s.z; S11 += s.w;
            mn00 = fminf(mn00, mnw.x); mn01 = fminf(mn01, mnw.y);
            mn10 = fminf(mn10, mnw.z); mn11 = fminf(mn11, mnw.w);
            mx00 = fmaxf(mx00, mxw.x); mx01 = fmaxf(mx01, mxw.y);
            mx10 = fmaxf(mx10, mxw.z); mx11 = fmaxf(mx11, mxw.w);
        }
        if (len < 512) {  // culled contribute w=0 (also fixes len==0 INFs)
            mn00 = fminf(mn00, 0.f); mn01 = fminf(mn01, 0.f);
            mn10 = fminf(mn10, 0.f); mn11 = fminf(mn11, 0.f);
            mx00 = fmaxf(mx00, 0.f); mx01 = fmaxf(mx01, 0.f);
            mx10 = fmaxf(mx10, 0.f); mx11 = fmaxf(mx11, 0.f);
        }
        // agent-scope scalar stores into SoA planes (4 floats per quad)
        const int fi = ((kk * 3 + v) * QOFF + yh * 112 + xh) * 4;
        g_st(part + fi + 0, S00);  g_st(part + fi + 1, S01);
        g_st(part + fi + 2, S10);  g_st(part + fi + 3, S11);
        g_st(part + MNOFF + fi + 0, mn00);  g_st(part + MNOFF + fi + 1, mn01);
        g_st(part + MNOFF + fi + 2, mn10);  g_st(part + MNOFF + fi + 3, mn11);
        g_st(part + MXOFF + fi + 0, mx00);  g_st(part + MXOFF + fi + 1, mx01);
        g_st(part + MXOFF + fi + 2, mx10);  g_st(part + MXOFF + fi + 3, mx11);
    }

    // ---- barrier A arrival (all 1176). __syncthreads drains every wave's
    // vmcnt (compiler-inserted s_waitcnt before s_barrier) -> stores at LLC.
    __syncthreads();
    if (tid == 0) {
        __hip_atomic_fetch_add(&cnts[CNTA_BASE + (bid6 & (NARR - 1)) * 32], 1u,
                               __ATOMIC_RELAXED, __HIP_MEMORY_SCOPE_AGENT);
    }
    if (kk == 1) return;  // splat-only blocks free their CU slots

    // ---- barrier A wait (588 kk==0 blocks) ----
    const int bid3 = v * 196 + (int)(blockIdx.y * 14 + blockIdx.x);
    if (tid == 0) {
        if (bid6 == 0) {
            for (;;) {
                unsigned s = 0;
                #pragma unroll
                for (int i = 0; i < NARR; ++i)
                    s += __hip_atomic_load(&cnts[CNTA_BASE + i * 32],
                                           __ATOMIC_RELAXED, __HIP_MEMORY_SCOPE_AGENT);
                if (s == NB_ALL) break;
                __builtin_amdgcn_s_sleep(2);
            }
            asm volatile("" ::: "memory");
            __hip_atomic_store(&cnts[FLAGA_IDX], 1u,
                               __ATOMIC_RELAXED, __HIP_MEMORY_SCOPE_AGENT);
        } else {
            while (__hip_atomic_load(&cnts[FLAGA_IDX], __ATOMIC_RELAXED,
                                     __HIP_MEMORY_SCOPE_AGENT) == 0u)
                __builtin_amdgcn_s_sleep(2);
        }
    }
    __syncthreads();

    // ============ phase 2: quad-grain merge + blur2 ============
    const float kw[7] = {0.00443305f, 0.05400558f, 0.24203623f, 0.39905030f,
                         0.24203623f, 0.05400558f, 0.00443305f};
    {
        const int qy0 = (ty0 - 6) >> 1, qx0 = (tx0 - 6) >> 1;  // even, exact
        if (tid < 196) {
            const int qr = tid / 14, qc = tid % 14;
            const int qgy = qy0 + qr, qgx = qx0 + qc;
            float dmv[4] = {0.0f, 0.0f, 0.0f, 0.0f};
            if (qgy >= 0 && qgy < 112 && qgx >= 0 && qgx < 112) {
                const int qb = (qgy * 112 + qgx) * 4;
                const int f0 = (0 * 3 + v) * QOFF * 4 + qb;
                const int f1 = (1 * 3 + v) * QOFF * 4 + qb;
                #pragma unroll
                for (int cc = 0; cc < 4; ++cc) {
                    float S  = g_ld(part + f0 + cc) + g_ld(part + f1 + cc);
                    float mn = fminf(g_ld(part + MNOFF + f0 + cc),
                                     g_ld(part + MNOFF + f1 + cc));
                    float mx = fmaxf(g_ld(part + MXOFF + f0 + cc),
                                     g_ld(part + MXOFF + f1 + cc));
                    dmv[cc] = 0.5f * (S - 512.0f * mn) / (mx - mn + 1e-6f)
                            + S / (S + 1e-6f);
                }
            }
            #pragma unroll
            for (int cc = 0; cc < 4; ++cc)
                sm.bl.A[(2 * qr + (cc >> 1)) * 29 + 2 * qc + (cc & 1)] = dmv[cc];
        }
    }
    __syncthreads();
    for (int idx = tid; idx < 22 * 28; idx += 256) {
        int rr = 3 + idx / 28, c = idx % 28;
        float s = 0.0f;
        #pragma unroll
        for (int i = 0; i < 7; ++i) s += kw[i] * sm.bl.A[(rr - 3 + i) * 29 + c];
        sm.bl.T[rr * 29 + c] = s;
    }
    __syncthreads();
    for (int idx = tid; idx < 22 * 22; idx += 256) {
        int rr = 3 + idx / 22, c = 3 + idx % 22;
        int gyy = ty0 - 6 + rr, gxx = tx0 - 6 + c;
        float s = 0.0f;
        #pragma unroll
        for (int j = 0; j < 7; ++j) s += kw[j] * sm.bl.T[rr * 29 + c - 3 + j];
        float ctr = sm.bl.A[rr * 29 + c];
        float d1 = ctr > 1e-6f ? ctr : s;
        if (gyy < 0 || gyy > 223 || gxx < 0 || gxx > 223) d1 = 0.0f;
        sm.bl.A[rr * 29 + c] = d1;
    }
    __syncthreads();
    for (int idx = tid; idx < 16 * 22; idx += 256) {
        int rr = 6 + idx / 22, c = 3 + idx % 22;
        float s = 0.0f;
        #pragma unroll
        for (int i = 0; i < 7; ++i) s += kw[i] * sm.bl.A[(rr - 3 + i) * 29 + c];
        sm.bl.T[rr * 29 + c] = s;
    }
    __syncthreads();
    const int rr2 = 6 + (tid >> 4), cc2 = 6 + (tid & 15);
    float d2;
    {
        float s = 0.0f;
        #pragma unroll
        for (int j = 0; j < 7; ++j) s += kw[j] * sm.bl.T[rr2 * 29 + cc2 - 3 + j];
        float ctr = sm.bl.A[rr2 * 29 + cc2];
        d2 = ctr > 1e-6f ? ctr : s;
    }
    float ls1 = d2, ls2 = d2 * d2;
    #pragma unroll
    for (int o = 32; o >= 1; o >>= 1) {
        ls1 += __shfl_xor(ls1, o);
        ls2 += __shfl_xor(ls2, o);
    }
    if (lane == 0) { sm.bl.r1[wave] = ls1; sm.bl.r2[wave] = ls2; }
    __syncthreads();
    if (tid == 0) {
        float a = sm.bl.r1[0] + sm.bl.r1[1] + sm.bl.r1[2] + sm.bl.r1[3];
        float b = sm.bl.r2[0] + sm.bl.r2[1] + sm.bl.r2[2] + sm.bl.r2[3];
        float* pb = (float*)&partials[bid3];
        g_st(pb + 0, a);
        g_st(pb + 1, b);
    }

    // ---- barrier B arrival ----
    __syncthreads();  // drains the partial stores of wave 0
    if (tid == 0) {
        __hip_atomic_fetch_add(&cnts[CNTB_BASE + (bid3 & (NARR - 1)) * 32], 1u,
                               __ATOMIC_RELAXED, __HIP_MEMORY_SCOPE_AGENT);
    }

    float fmean, finv;
    if (bid3 == 0) {
        if (tid == 0) {
            for (;;) {
                unsigned s = 0;
                #pragma unroll
                for (int i = 0; i < NARR; ++i)
                    s += __hip_atomic_load(&cnts[CNTB_BASE + i * 32],
                                           __ATOMIC_RELAXED, __HIP_MEMORY_SCOPE_AGENT);
                if (s == NB_BLUR) break;
                __builtin_amdgcn_s_sleep(2);
            }
        }
        __syncthreads();
        double a = 0.0, b = 0.0;
        const float* pb = (const float*)partials;
        for (int i = tid; i < 588; i += 256) {
            a += (double)g_ld(pb + 2 * i);
            b += (double)g_ld(pb + 2 * i + 1);
        }
        sm.nm.s1[tid] = a; sm.nm.s2[tid] = b;
        __syncthreads();
        for (int s = 128; s >= 1; s >>= 1) {
            if (tid < s) { sm.nm.s1[tid] += sm.nm.s1[tid + s]; sm.nm.s2[tid] += sm.nm.s2[tid + s]; }
            __syncthreads();
        }
        const double M = 150528.0;
        double mean = sm.nm.s1[0] / M;
        double var = (sm.nm.s2[0] - M * mean * mean) / (M - 1.0);
        double sd = sqrt(var > 0.0 ? var : 0.0);
        fmean = (float)mean;
        finv = 1.0f / ((float)sd + 1e-6f);
        if (tid == 0) {
            float* st = (float*)&cnts[STAT_IDX];
            g_st(st + 0, fmean);
            g_st(st + 1, finv);
            asm volatile("s_waitcnt vmcnt(0)" ::: "memory");  // stats before flag
            __hip_atomic_store(&cnts[FLAGB_IDX], 1u,
                               __ATOMIC_RELAXED, __HIP_MEMORY_SCOPE_AGENT);
        }
    } else {
        if (tid == 0) {
            while (__hip_atomic_load(&cnts[FLAGB_IDX], __ATOMIC_RELAXED,
                                     __HIP_MEMORY_SCOPE_AGENT) == 0u)
                __builtin_amdgcn_s_sleep(2);
            const float* st = (const float*)&cnts[STAT_IDX];
            sm.nm.statLds[0] = g_ld(st + 0);
            sm.nm.statLds[1] = g_ld(st + 1);
        }
        __syncthreads();
        fmean = sm.nm.statLds[0];
        finv = sm.nm.statLds[1];
    }

    out[(v * 224 + ty0 + (tid >> 4)) * 224 + tx0 + (tid & 15)] =
        (d2 - fmean) * finv;
}

extern "C" void kernel_launch(void* const* d_in, const int* in_sizes, int n_in,
                              void* d_out, int out_size, void* d_ws, size_t ws_size,
                              hipStream_t stream) {
    const float* position   = (const float*)d_in[0];  // (1,512,3)
    const float* cov3d      = (const float*)d_in[1];  // (1,512,3,3)
    const float* opacity    = (const float*)d_in[2];  // (1,512)
    const float* importance = (const float*)d_in[3];  // (1,1000)
    float* out = (float*)d_out;                       // (1,3,224,224)

    float* part      = (float*)d_ws;                            // 903168 floats
    float2* partials = (float2*)((float*)d_ws + 903168);        // 588 float2
    unsigned* cnts   = (unsigned*)((float*)d_ws + 903168 + 1176);  // 2144 u32

    hipMemsetAsync(cnts, 0, CNTS_U32 * sizeof(unsigned), stream);
    hipLaunchKernelGGL(fused_kernel, dim3(14, 14, 6), dim3(256), 0, stream,
                       position, cov3d, opacity, importance, part, partials,
                       out, cnts);
}

// Round 9
// 89.761 us; speedup vs baseline: 1.0903x; 1.0903x over previous
//
#include <hip/hip_runtime.h>
#include <math.h>

// ---------------------------------------------------------------------------
// FullGaussianProjector: B=1, N=512, 3 views, 224x224 out, half-res 112x112.
// R14 = R9/R4 verbatim (session-best artifact, 90.25us @ fill=40.0): control
// re-run at current clocks. Experiment matrix (R0..R13): five structures
// (3/2/1 dispatches, cheap barriers, KSPLIT splits, hoisted setup, coalesced
// exchange) all measure 90+-1us clock-normalized; marginal kernel cost shows
// 1:1 in dur_us, so the invariance is real. Floor = 40us harness poison fill
// (84% HBM peak) + ~15us fixed overhead + ~35us kernel-time invariant.
//   kernel 1 (splat, 512 thr): per-tile cull/compact + quad eval, no grid
//     barrier -> hardware dynamically rebalances non-uniform tiles. Clears
//     kernel-2 barrier counters (kernel-boundary flush orders it).
//   kernel 2 (blur2 + stats + normalize, 256 thr): blur uniform per block;
//     cheap LLC grid barrier: arrival spread over 32 cachelines (parallel
//     TCC channels), single poller sums+sets flag, others spin READ-ONLY.
//     All barrier traffic relaxed agent-scope (LLC-coherent, no cache
//     maintenance). d2 stays in registers across the barrier; out written
//     exactly once.
// Closed forms:
//   dmv = 0.5*(S - 512*mn)/(mx - mn + eps) + S/(S + eps)
//   bilinear(quadratic) = quad(Ex,Ey) - (a*Vx + c*Vy)
// NOTE (R5 lesson): a,2b,c,op must stay f32 — bf16 on the exponent path
// fails absmax through the (wmax-wmin) normalization.
// ---------------------------------------------------------------------------

#define NBLOCKS 588u
#define NARR 32          // arrival counters, one per 128B cacheline
#define FLAG_IDX (NARR * 32)   // release flag, its own cacheline

__device__ __forceinline__ float g_ld(const float* p) {
    return __hip_atomic_load(p, __ATOMIC_RELAXED, __HIP_MEMORY_SCOPE_AGENT);
}
__device__ __forceinline__ void g_st(float* p, float v) {
    __hip_atomic_store(p, v, __ATOMIC_RELAXED, __HIP_MEMORY_SCOPE_AGENT);
}

// Cheap grid barrier: spread arrival + single poller + broadcast release.
// No cache maintenance; cross-block data must use agent-scope atomics.
__device__ __forceinline__ void grid_barrier(unsigned* cnts, int arrIdx, bool poller) {
    __syncthreads();
    if (threadIdx.x == 0) {
        asm volatile("s_waitcnt vmcnt(0)" ::: "memory");  // partials acked at LLC
        __hip_atomic_fetch_add(&cnts[arrIdx * 32], 1u,
                               __ATOMIC_RELAXED, __HIP_MEMORY_SCOPE_AGENT);
        unsigned* flagp = &cnts[FLAG_IDX];
        if (poller) {
            for (;;) {
                unsigned s = 0;
                #pragma unroll
                for (int i = 0; i < NARR; ++i)
                    s += __hip_atomic_load(&cnts[i * 32],
                                           __ATOMIC_RELAXED, __HIP_MEMORY_SCOPE_AGENT);
                if (s == NBLOCKS) break;
                __builtin_amdgcn_s_sleep(2);
            }
            asm volatile("" ::: "memory");  // flag store after poll loads
            __hip_atomic_store(flagp, 1u, __ATOMIC_RELAXED, __HIP_MEMORY_SCOPE_AGENT);
        } else {
            while (__hip_atomic_load(flagp, __ATOMIC_RELAXED,
                                     __HIP_MEMORY_SCOPE_AGENT) == 0u)
                __builtin_amdgcn_s_sleep(2);
        }
    }
    __syncthreads();
}

__device__ __forceinline__ float wave_min(float v) {
    #pragma unroll
    for (int o = 32; o >= 1; o >>= 1) v = fminf(v, __shfl_xor(v, o));
    return v;
}

// Block: 512 threads (8 waves), tile 16x16 full-res px (8x8 quads), grid (14,14,3).
__global__ __launch_bounds__(512) void splat_fused_kernel(
    const float* __restrict__ position, const float* __restrict__ cov3d,
    const float* __restrict__ opacity, const float* __restrict__ importance,
    float* __restrict__ dm, unsigned* __restrict__ cnts) {
    __shared__ float4 lsA[512];        // a, 2b, c, op
    __shared__ float2 lsB[512];        // gx, gy
    __shared__ float red[8 * 6];       // cross-wave min/max scratch
    __shared__ float4 pS[7][64], pMn[7][64], pMx[7][64];
    __shared__ int cnt;
    const int v = blockIdx.z;
    const int tx0 = blockIdx.x * 16, ty0 = blockIdx.y * 16;
    const int tid = threadIdx.x;
    const int lane = tid & 63, wave = tid >> 6;

    // clear kernel-2 barrier counters + flag (ws is poisoned each iteration;
    // the kernel boundary flush makes this visible before kernel 2 starts)
    if (blockIdx.x == 0 && blockIdx.y == 0 && blockIdx.z == 0) {
        for (int i = tid; i <= FLAG_IDX; i += 512) cnts[i] = 0;
    }

    // ---------------- setup (1 gaussian per thread) ----------------
    const int n = tid;
    const float p0 = position[n * 3 + 0];
    const float p1 = position[n * 3 + 1];
    const float p2 = position[n * 3 + 2];
    const float opimp = opacity[n] * fminf(fmaxf(importance[n], 0.5f), 2.0f);

    {
        float vals[6] = {p0, -p0, p1, -p1, p2, -p2};
        #pragma unroll
        for (int k = 0; k < 6; ++k) {
            float r = wave_min(vals[k]);
            if (lane == 0) red[wave * 6 + k] = r;
        }
    }
    __syncthreads();
    float mn6[6];
    #pragma unroll
    for (int k = 0; k < 6; ++k) {
        float r = red[k];
        #pragma unroll
        for (int w = 1; w < 8; ++w) r = fminf(r, red[w * 6 + k]);
        mn6[k] = r;
    }
    const float pmn[3] = {mn6[0], mn6[2], mn6[4]};
    const float pmx[3] = {-mn6[1], -mn6[3], -mn6[5]};

    float c00 = cov3d[n * 9 + 0], c01 = cov3d[n * 9 + 1], c02 = cov3d[n * 9 + 2];
    float c10 = cov3d[n * 9 + 3], c11 = cov3d[n * 9 + 4], c12 = cov3d[n * 9 + 5];
    float c20 = cov3d[n * 9 + 6], c21 = cov3d[n * 9 + 7], c22 = cov3d[n * 9 + 8];
    for (int vv = 0; vv <= v; ++vv) {
        float s01 = 0.5f * (c01 + c10);
        float s02 = 0.5f * (c02 + c20);
        float s12 = 0.5f * (c12 + c21);
        float s00 = c00 + 1e-6f;
        float s11 = c11 + 1e-6f;
        float s22 = c22 + 1e-6f;
        float nrm = sqrtf(s00 * s00 + s11 * s11 + s22 * s22 +
                          2.0f * (s01 * s01 + s02 * s02 + s12 * s12));
        float inv = 1.0f / (nrm + 1e-6f);
        c00 = s00 * inv; c11 = s11 * inv; c22 = s22 * inv;
        c01 = s01 * inv; c10 = c01; c02 = s02 * inv; c20 = c02;
        c12 = s12 * inv; c21 = c12;
    }
    float cof00 = c11 * c22 - c12 * c12;
    float cof01 = c02 * c12 - c01 * c22;
    float cof02 = c01 * c12 - c02 * c11;
    float det = c00 * cof00 + c01 * cof01 + c02 * cof02;
    float idet = 1.0f / det;
    float i00 = cof00 * idet;
    float i01 = cof01 * idet;
    float i02 = cof02 * idet;
    float i11 = (c00 * c22 - c02 * c02) * idet;
    float i12 = (c02 * c01 - c00 * c12) * idet;
    float i22 = (c00 * c11 - c01 * c01) * idet;

    float Aa, Ab, Ac, prx, pry;
    int ix, iy;
    if (v == 0)      { Aa = i00; Ab = i01; Ac = i11; prx = p0; pry = p1; ix = 0; iy = 1; }
    else if (v == 1) { Aa = i00; Ab = i02; Ac = i22; prx = p0; pry = p2; ix = 0; iy = 2; }
    else             { Aa = i22; Ab = i12; Ac = i11; prx = p2; pry = p1; ix = 2; iy = 1; }
    Aa += 1e-10f;
    Ac += 1e-10f;

    float mnx = pmn[ix], mxx = pmx[ix], mny = pmn[iy], mxy = pmx[iy];
    float rngx = mxx - mnx + 1e-6f;
    float mnx2 = mnx - 0.5f * rngx;
    float mxx2 = mxx + 0.5f * rngx;
    rngx = mxx2 - mnx2 + 1e-6f;
    float rngy = mxy - mny + 1e-6f;
    float mny2 = mny - 0.5f * rngy;
    float mxy2 = mxy + 0.5f * rngy;
    rngy = mxy2 - mny2 + 1e-6f;
    float gx = fminf(fmaxf((prx - mnx2) / rngx * 111.0f, 0.0f), 111.0f);
    float gy = fminf(fmaxf((pry - mny2) / rngy * 111.0f, 0.0f), 111.0f);

    // ---------------- cull + compact into LDS (SoA f32) ----------------
    if (tid == 0) cnt = 0;
    __syncthreads();
    {
        const float bx0 = (float)(tx0 >> 1), bx1 = (float)((tx0 + 15) >> 1);
        const float by0 = (float)(ty0 >> 1), by1 = (float)((ty0 + 15) >> 1);
        float dx = fmaxf(fmaxf(bx0 - gx, gx - bx1), 0.0f);
        float dy = fmaxf(fmaxf(by0 - gy, gy - by1), 0.0f);
        bool pass = (dx * dx + dy * dy) < 400.01f;  // conservative superset
        unsigned long long m = __ballot(pass);
        int base = 0;
        if (lane == 0) base = atomicAdd(&cnt, __popcll(m));
        base = __shfl(base, 0);
        if (pass) {
            int slot = base + __popcll(m & ((1ull << lane) - 1ull));
            lsA[slot] = make_float4(Aa, 2.0f * Ab, Ac, opimp);
            lsB[slot] = make_float2(gx, gy);
        }
    }
    __syncthreads();
    const int len = cnt;

    // quad owned by this lane: half-res pixel (xh, yh)
    const int qx = lane & 7, qy = lane >> 3;
    const int xh = (tx0 >> 1) + qx;
    const int yh = (ty0 >> 1) + qy;

    if (len == 0) {  // uniform branch: whole block exits
        if (wave == 0) {
            #pragma unroll
            for (int py = 0; py < 2; ++py)
                #pragma unroll
                for (int px = 0; px < 2; ++px)
                    dm[(v * 224 + ty0 + 2 * qy + py) * 224 + tx0 + 2 * qx + px] = 0.0f;
        }
        return;
    }

    const int npad = (len + 15) & ~15;
    if (tid < npad - len) {  // no-op pad gaussians (mask always fails -> w=0)
        lsA[len + tid] = make_float4(1.0f, 0.0f, 1.0f, 0.0f);
        lsB[len + tid] = make_float2(1e9f, 1e9f);
    }
    __syncthreads();

    // per-parity constants (generic formula, preserves edge clamping exactly)
    float exA[2], eyA[2], VxA[2], VyA[2];
    #pragma unroll
    for (int p = 0; p < 2; ++p) {
        int xlo = xh - 1 + p; int xhi = min(xlo + 1, 111); xlo = max(xlo, 0);
        float wlo = p ? 0.75f : 0.25f, whi = 1.0f - wlo;
        exA[p] = wlo * (float)xlo + whi * (float)xhi;
        VxA[p] = wlo * whi * (float)(xhi - xlo) * (float)(xhi - xlo);
        int ylo = yh - 1 + p; int yhi2 = min(ylo + 1, 111); ylo = max(ylo, 0);
        eyA[p] = wlo * (float)ylo + whi * (float)yhi2;
        VyA[p] = wlo * whi * (float)(yhi2 - ylo) * (float)(yhi2 - ylo);
    }
    const float fxh = (float)xh, fyh = (float)yh;

    // ---------------- list chunk for this wave, quad eval ----------------
    const int chunk = npad >> 3;           // multiple of 2
    const int cbeg = wave * chunk, cend = cbeg + chunk;

    float S00 = 0.f, S01 = 0.f, S10 = 0.f, S11 = 0.f;
    float mn00 = INFINITY, mn01 = INFINITY, mn10 = INFINITY, mn11 = INFINITY;
    float mx00 = -INFINITY, mx01 = -INFINITY, mx10 = -INFINITY, mx11 = -INFINITY;

    for (int i = cbeg; i < cend; i += 2) {
        float4 gA0 = lsA[i], gA1 = lsA[i + 1];
        float2 gB0 = lsB[i], gB1 = lsB[i + 1];
        #pragma unroll
        for (int u = 0; u < 2; ++u) {
            const float4 gA = u ? gA1 : gA0;
            const float2 gB = u ? gB1 : gB0;
            const float a = gA.x, b2 = gA.y, c = gA.z, op = gA.w;
            const float xx = gB.x, yy = gB.y;
            const float dxh = fxh - xx, dyh = fyh - yy;
            const bool inside = dxh * dxh + dyh * dyh < 400.0f;
            const float dx0 = exA[0] - xx, dx1 = exA[1] - xx;
            const float dy0 = eyA[0] - yy, dy1 = eyA[1] - yy;
            const float adx0 = a * dx0, adx1 = a * dx1;
            const float bdy0 = b2 * dy0, bdy1 = b2 * dy1;
            const float cdy0 = c * dy0 * dy0, cdy1 = c * dy1 * dy1;
            const float ax0 = a * VxA[0], ax1 = a * VxA[1];
            const float cy0 = c * VyA[0], cy1 = c * VyA[1];
            #pragma unroll
            for (int py = 0; py < 2; ++py) {
                const float bdyp = py ? bdy1 : bdy0;
                const float cdyp = py ? cdy1 : cdy0;
                const float cyp  = py ? cy1 : cy0;
                #pragma unroll
                for (int px = 0; px < 2; ++px) {
                    const float dxp  = px ? dx1 : dx0;
                    const float adxp = px ? adx1 : adx0;
                    const float axp  = px ? ax1 : ax0;
                    float q = dxp * (adxp + bdyp) + cdyp;
                    float bil = -((q + axp) + cyp);
                    bil = fminf(fmaxf(bil, -20.0f), 0.0f);
                    bil = inside ? bil : -1e9f;   // exp flushes to +0
                    float w = op * __expf(bil);
                    if (py == 0 && px == 0) { S00 += w; mn00 = fminf(mn00, w); mx00 = fmaxf(mx00, w); }
                    if (py == 0 && px == 1) { S01 += w; mn01 = fminf(mn01, w); mx01 = fmaxf(mx01, w); }
                    if (py == 1 && px == 0) { S10 += w; mn10 = fminf(mn10, w); mx10 = fmaxf(mx10, w); }
                    if (py == 1 && px == 1) { S11 += w; mn11 = fminf(mn11, w); mx11 = fmaxf(mx11, w); }
                }
            }
        }
    }
    if (wave > 0) {
        pS[wave - 1][lane]  = make_float4(S00, S01, S10, S11);
        pMn[wave - 1][lane] = make_float4(mn00, mn01, mn10, mn11);
        pMx[wave - 1][lane] = make_float4(mx00, mx01, mx10, mx11);
    }
    __syncthreads();
    if (wave == 0) {
        #pragma unroll
        for (int k = 0; k < 7; ++k) {
            float4 s = pS[k][lane], m = pMn[k][lane], M = pMx[k][lane];
            S00 += s.x; S01 += s.y; S10 += s.z; S11 += s.w;
            mn00 = fminf(mn00, m.x); mn01 = fminf(mn01, m.y);
            mn10 = fminf(mn10, m.z); mn11 = fminf(mn11, m.w);
            mx00 = fmaxf(mx00, M.x); mx01 = fmaxf(mx01, M.y);
            mx10 = fmaxf(mx10, M.z); mx11 = fmaxf(mx11, M.w);
        }
        if (len < 512) {
            mn00 = fminf(mn00, 0.f); mn01 = fminf(mn01, 0.f);
            mn10 = fminf(mn10, 0.f); mn11 = fminf(mn11, 0.f);
            mx00 = fmaxf(mx00, 0.f); mx01 = fmaxf(mx01, 0.f);
            mx11 = fmaxf(mx11, 0.f); mx10 = fmaxf(mx10, 0.f);
        }
        float S4[4]  = {S00, S01, S10, S11};
        float mn4[4] = {mn00, mn01, mn10, mn11};
        float mx4[4] = {mx00, mx01, mx10, mx11};
        #pragma unroll
        for (int pp = 0; pp < 4; ++pp) {
            float S = S4[pp];
            float dmv = 0.5f * (S - 512.0f * mn4[pp]) / (mx4[pp] - mn4[pp] + 1e-6f)
                      + S / (S + 1e-6f);
            const int py = pp >> 1, px = pp & 1;
            dm[(v * 224 + ty0 + 2 * qy + py) * 224 + tx0 + 2 * qx + px] = dmv;
        }
    }
}

// Fused: d1 = where(d, blur(d)); d2 = where(d1, blur(d1));
// per-block partial (sum, sumsq) -> partials -> cheap LLC barrier -> every
// block reduces 588 partials (double) and writes out = (d2-mean)/(sd+eps)
// from registers. Tile 16x16 + halo 6; blur work is UNIFORM so the barrier
// costs only sync latency. dm read with plain loads (kernel boundary flush).
__global__ __launch_bounds__(256, 3) void blur_norm_kernel(
    const float* __restrict__ in, float* __restrict__ out,
    float2* __restrict__ partials, unsigned* __restrict__ cnts) {
    __shared__ float A[28 * 29];
    __shared__ float T[28 * 29];
    __shared__ float r1[4], r2[4];
    __shared__ double s1[256], s2[256];
    const int v = blockIdx.z;
    const int tx0 = blockIdx.x * 16, ty0 = blockIdx.y * 16;
    const int tid = threadIdx.x;
    const int lane = tid & 63, wave = tid >> 6;
    const int bid = (v * 14 + blockIdx.y) * 14 + blockIdx.x;
    const float kw[7] = {0.00443305f, 0.05400558f, 0.24203623f, 0.39905030f,
                         0.24203623f, 0.05400558f, 0.00443305f};
    const float* __restrict__ chan = in + v * 224 * 224;

    for (int idx = tid; idx < 28 * 28; idx += 256) {
        int rr = idx / 28, c = idx % 28;
        int gyy = ty0 - 6 + rr, gxx = tx0 - 6 + c;
        float val = 0.0f;
        if (gyy >= 0 && gyy < 224 && gxx >= 0 && gxx < 224) val = chan[gyy * 224 + gxx];
        A[rr * 29 + c] = val;
    }
    __syncthreads();
    for (int idx = tid; idx < 22 * 28; idx += 256) {
        int rr = 3 + idx / 28, c = idx % 28;
        float s = 0.0f;
        #pragma unroll
        for (int i = 0; i < 7; ++i) s += kw[i] * A[(rr - 3 + i) * 29 + c];
        T[rr * 29 + c] = s;
    }
    __syncthreads();
    for (int idx = tid; idx < 22 * 22; idx += 256) {
        int rr = 3 + idx / 22, c = 3 + idx % 22;
        int gyy = ty0 - 6 + rr, gxx = tx0 - 6 + c;
        float s = 0.0f;
        #pragma unroll
        for (int j = 0; j < 7; ++j) s += kw[j] * T[rr * 29 + c - 3 + j];
        float ctr = A[rr * 29 + c];
        float d1 = ctr > 1e-6f ? ctr : s;
        if (gyy < 0 || gyy > 223 || gxx < 0 || gxx > 223) d1 = 0.0f;
        A[rr * 29 + c] = d1;
    }
    __syncthreads();
    for (int idx = tid; idx < 16 * 22; idx += 256) {
        int rr = 6 + idx / 22, c = 3 + idx % 22;
        float s = 0.0f;
        #pragma unroll
        for (int i = 0; i < 7; ++i) s += kw[i] * A[(rr - 3 + i) * 29 + c];
        T[rr * 29 + c] = s;
    }
    __syncthreads();
    // one output px per thread; KEEP d2 in a register across the barrier
    const int rr2 = 6 + (tid >> 4), cc2 = 6 + (tid & 15);
    float d2;
    {
        float s = 0.0f;
        #pragma unroll
        for (int j = 0; j < 7; ++j) s += kw[j] * T[rr2 * 29 + cc2 - 3 + j];
        float ctr = A[rr2 * 29 + cc2];
        d2 = ctr > 1e-6f ? ctr : s;
    }
    float ls1 = d2, ls2 = d2 * d2;
    #pragma unroll
    for (int o = 32; o >= 1; o >>= 1) {
        ls1 += __shfl_xor(ls1, o);
        ls2 += __shfl_xor(ls2, o);
    }
    if (lane == 0) { r1[wave] = ls1; r2[wave] = ls2; }
    __syncthreads();
    if (tid == 0) {
        float a = r1[0] + r1[1] + r1[2] + r1[3];
        float b = r2[0] + r2[1] + r2[2] + r2[3];
        float* pb = (float*)&partials[bid];
        g_st(pb + 0, a);
        g_st(pb + 1, b);
    }

    grid_barrier(cnts, bid & (NARR - 1), bid == 0);  // partials visible at LLC

    // global stats from 588 partials (double), then normalize from registers
    double a = 0.0, b = 0.0;
    const float* pb = (const float*)partials;
    for (int i = tid; i < 588; i += 256) {
        a += (double)g_ld(pb + 2 * i);
        b += (double)g_ld(pb + 2 * i + 1);
    }
    s1[tid] = a; s2[tid] = b;
    __syncthreads();
    for (int s = 128; s >= 1; s >>= 1) {
        if (tid < s) { s1[tid] += s1[tid + s]; s2[tid] += s2[tid + s]; }
        __syncthreads();
    }
    const double M = 150528.0;
    double mean = s1[0] / M;
    double var = (s2[0] - M * mean * mean) / (M - 1.0);
    double sd = sqrt(var > 0.0 ? var : 0.0);
    const float fmean = (float)mean;
    const float finv = 1.0f / ((float)sd + 1e-6f);
    out[(v * 224 + ty0 + (tid >> 4)) * 224 + tx0 + (tid & 15)] =
        (d2 - fmean) * finv;
}

extern "C" void kernel_launch(void* const* d_in, const int* in_sizes, int n_in,
                              void* d_out, int out_size, void* d_ws, size_t ws_size,
                              hipStream_t stream) {
    const float* position   = (const float*)d_in[0];  // (1,512,3)
    const float* cov3d      = (const float*)d_in[1];  // (1,512,3,3)
    const float* opacity    = (const float*)d_in[2];  // (1,512)
    const float* importance = (const float*)d_in[3];  // (1,1000)
    float* out = (float*)d_out;                       // (1,3,224,224)

    float* dmA       = (float*)d_ws;                          // 150528 floats
    float2* partials = (float2*)((float*)d_ws + 150528);      // 588 float2
    unsigned* cnts   = (unsigned*)((float*)d_ws + 150528 + 1176);  // 1025 u32

    hipLaunchKernelGGL(splat_fused_kernel, dim3(14, 14, 3), dim3(512), 0, stream,
                       position, cov3d, opacity, importance, dmA, cnts);
    hipLaunchKernelGGL(blur_norm_kernel, dim3(14, 14, 3), dim3(256), 0, stream,
                       dmA, out, partials, cnts);
}